// Round 8
// baseline (712.532 us; speedup 1.0000x reference)
//
#include <hip/hip_runtime.h>

#define D 128
#define RSQRT_D 0.088388347648318440550f  // 1/sqrt(128)
#define NEG_HUGE -3.4e38f
#define NPB 8     // nodes per block (2 waves x 4 nodes)
#define CAP 288   // LDS-cached edge indices per block (mean demand 128, +14 sigma)
#define DTHR 20.0f  // defer-max rescale threshold

#define FMA4(acc, s, b) { acc.x += (s)*(b).x; acc.y += (s)*(b).y; acc.z += (s)*(b).z; acc.w += (s)*(b).w; }
#define ADD4(acc, b) { acc.x += (b).x; acc.y += (b).y; acc.z += (b).z; acc.w += (b).w; }
#define MRG4(a) { a.x += __shfl_xor(a.x,32); a.y += __shfl_xor(a.y,32); a.z += __shfl_xor(a.z,32); a.w += __shfl_xor(a.w,32); }
#define SCL4(a, f) { a.x *= (f); a.y *= (f); a.z *= (f); a.w *= (f); }
#define Z4 make_float4(0.f,0.f,0.f,0.f)

// merge softmax state (m,s,c) across the two half-waves
#define MERGE_HALVES(mi, si, ci) { \
    float mo_ = __shfl_xor(mi, 32); \
    float so_ = __shfl_xor(si, 32); \
    float4 co_; co_.x = __shfl_xor(ci.x, 32); co_.y = __shfl_xor(ci.y, 32); \
    co_.z = __shfl_xor(ci.z, 32); co_.w = __shfl_xor(ci.w, 32); \
    float mt_ = fmaxf(mi, mo_); \
    float e0_ = __expf(mi - mt_), e1_ = __expf(mo_ - mt_); \
    si = si * e0_ + so_ * e1_; \
    ci.x = ci.x * e0_ + co_.x * e1_; ci.y = ci.y * e0_ + co_.y * e1_; \
    ci.z = ci.z * e0_ + co_.z * e1_; ci.w = ci.w * e0_ + co_.w * e1_; \
}

// ---------------- prep: weight folds + zero cnt/cursor ----------------
__global__ __launch_bounds__(256) void prep_kernel(
    const float* __restrict__ Wq, const float* __restrict__ Wk,
    const float* __restrict__ bq, const float* __restrict__ bk,
    const float* __restrict__ Wv, const float* __restrict__ Wo,
    const float* __restrict__ bv,
    float* __restrict__ Wqk, float* __restrict__ bqk,
    float* __restrict__ wqb, float* __restrict__ bqb,
    float* __restrict__ Wvo, float* __restrict__ bvo,
    int* __restrict__ zbase, int zcount) {
    int bid = blockIdx.x, t = threadIdx.x;
    if (bid < 64) {
        int i = bid * 2 + (t >> 7), j = t & 127;
        float a1 = 0.f, a2 = 0.f;
        for (int u = 0; u < D; ++u) {
            a1 += Wq[i * D + u] * Wk[j * D + u];   // (Wq @ Wk^T)[i][j]
            a2 += Wv[i * D + u] * Wo[u * D + j];   // (Wv @ Wo)[i][j]
        }
        Wqk[i * D + j] = a1;
        Wvo[i * D + j] = a2;
    } else if (bid == 64) {
        if (t < D) {
            int j = t;
            float a1 = 0.f, a2 = 0.f, a3 = 0.f;
            for (int u = 0; u < D; ++u) {
                a1 += bq[u] * Wk[j * D + u];       // bq @ Wk^T
                a2 += Wq[j * D + u] * bk[u];       // Wq @ bk
                a3 += bv[u] * Wo[u * D + j];       // bv @ Wo
            }
            bqk[j] = a1; wqb[j] = a2; bvo[j] = a3;
            if (j == 0) {
                float b = 0.f;
                for (int u = 0; u < D; ++u) b += bq[u] * bk[u];
                *bqb = b;
            }
        }
    } else {
        int idx = (bid - 65) * 256 + t;
        if (idx < zcount) zbase[idx] = 0;
    }
}

// ---------------- CSR: histogram (int4 recv loads; counts are order-invariant) ----------------
__global__ void hist_kernel(const int* __restrict__ recv, int* __restrict__ cnt, int E) {
    int i = blockIdx.x * blockDim.x + threadIdx.x;
    int base = i << 2;
    if (base + 3 < E) {
        int4 r = *(const int4*)(recv + base);
        atomicAdd(&cnt[r.x], 1);
        atomicAdd(&cnt[r.y], 1);
        atomicAdd(&cnt[r.z], 1);
        atomicAdd(&cnt[r.w], 1);
    } else {
        for (int u = base; u < E; ++u) atomicAdd(&cnt[recv[u]], 1);
    }
}

// ---------------- CSR: single-block exclusive scan (int4-wide, prefetched) ----------------
__global__ __launch_bounds__(1024) void scan_kernel(const int* __restrict__ cnt,
                                                    int* __restrict__ start, int N) {
    __shared__ int wsum[16];
    __shared__ int chunk_total;
    int t = threadIdx.x;
    int w = t >> 6, lane = t & 63;
    int running = 0;
    const int4* cnt4 = (const int4*)cnt;
    int nIter = (N + 4095) >> 12;   // 4096 elems per iteration
    int4 v = make_int4(0, 0, 0, 0);
    {
        int i = t << 2;
        if (i < N) v = cnt4[i >> 2];   // N % 4 == 0
    }
    for (int it = 0; it < nIter; ++it) {
        int4 vn = make_int4(0, 0, 0, 0);
        {
            int i = ((it + 1) << 12) + (t << 2);
            if (it + 1 < nIter && i < N) vn = cnt4[i >> 2];
        }
        int s0 = v.x, s1 = s0 + v.y, s2 = s1 + v.z, s3 = s2 + v.w;  // thread-local inclusive
        int x = s3;
#pragma unroll
        for (int off = 1; off < 64; off <<= 1) {
            int y = __shfl_up(x, off);
            if (lane >= off) x += y;
        }
        if (lane == 63) wsum[w] = x;
        __syncthreads();
        if (w == 0 && lane < 16) {
            int s = wsum[lane];
#pragma unroll
            for (int off = 1; off < 16; off <<= 1) {
                int y = __shfl_up(s, off);
                if (lane >= off) s += y;
            }
            wsum[lane] = s;  // inclusive
            if (lane == 15) chunk_total = s;
        }
        __syncthreads();
        int waveoff = (w == 0) ? 0 : wsum[w - 1];
        int tb = running + waveoff + (x - s3);  // exclusive base for this thread's 4
        int i = (it << 12) + (t << 2);
        if (i < N) ((int4*)start)[i >> 2] = make_int4(tb, tb + s0, tb + s1, tb + s2);
        running += chunk_total;
        __syncthreads();
        v = vn;
    }
    if (t == 0) start[N] = running;
}

// ---------------- CSR: fill edge index lists (kept 1-thread/edge: preserves edge order) ----------------
__global__ void fill_kernel(const int* __restrict__ recv, const int* __restrict__ start,
                            int* __restrict__ cursor, int* __restrict__ eidx, int E) {
    int e = blockIdx.x * blockDim.x + threadIdx.x;
    if (e >= E) return;
    int r = recv[e];
    int p = atomicAdd(&cursor[r], 1);
    eidx[start[r] + p] = e;
}

// cross-half-wave dot: 32-lane reduce of per-lane float4 partial
__device__ __forceinline__ float hdot32(float4 f, float4 q) {
    float p = f.x * q.x + f.y * q.y + f.z * q.z + f.w * q.w;
    p += __shfl_xor(p, 1); p += __shfl_xor(p, 2); p += __shfl_xor(p, 4);
    p += __shfl_xor(p, 8); p += __shfl_xor(p, 16);
    return p;
}

// P1 per-row step; when PERM, first stream the raw row to perm[] (coalesced store)
#define P1STEP(u, Fx) { \
    int r = j + h + 2 * (u); \
    float4 g_ = Fx; \
    if (PERM && r < b4) perm4w[(size_t)(s0B + r) * 32 + k] = g_; \
    float mk_ = (r < b4) ? 1.f : 0.f; \
    g_.x *= mk_; g_.y *= mk_; g_.z *= mk_; g_.w *= mk_; \
    if (r < b1)      { ADD4(a0, g_); } \
    else if (r < b2) { ADD4(a1, g_); } \
    else if (r < b3) { ADD4(a2, g_); } \
    else             { ADD4(a3, g_); } \
}

// P3 per-row step: score -> defer-max -> weighted accumulate
#define P3STEP(u, Fx) { \
    int r = j + h + 2 * (u); \
    bool valid_ = r < b4; \
    float4 f_ = Fx; \
    float4 qv_ = (r < b1) ? q0 : (r < b2) ? q1 : (r < b3) ? q2 : q3; \
    float qbv_ = (r < b1) ? qb0 : (r < b2) ? qb1 : (r < b3) ? qb2 : qb3; \
    float sc_ = (hdot32(f_, qv_) + qbv_) * RSQRT_D; \
    float msel_ = (r < b1) ? m0 : (r < b2) ? m1 : (r < b3) ? m2 : m3; \
    if (valid_ && sc_ > msel_ + DTHR) { \
        float fac_ = __expf(msel_ - sc_); \
        if (r < b1)      { sm0 *= fac_; SCL4(c0, fac_); m0 = sc_; } \
        else if (r < b2) { sm1 *= fac_; SCL4(c1, fac_); m1 = sc_; } \
        else if (r < b3) { sm2 *= fac_; SCL4(c2, fac_); m2 = sc_; } \
        else             { sm3 *= fac_; SCL4(c3, fac_); m3 = sc_; } \
        msel_ = sc_; \
    } \
    float wgt_ = valid_ ? __expf(sc_ - msel_) : 0.f; \
    if (r < b1)      { sm0 += wgt_; FMA4(c0, wgt_, f_); } \
    else if (r < b2) { sm1 += wgt_; FMA4(c1, wgt_, f_); } \
    else if (r < b3) { sm2 += wgt_; FMA4(c2, wgt_, f_); } \
    else             { sm3 += wgt_; FMA4(c3, wgt_, f_); } \
}

// ---------------- mega: gather+perm-stream sums -> qk -> defer-max softmax -> out ----------------
// Round-5 geometry (proven: 56 VGPR, no spill, ~40% occ). PERM=1: P1's gather ALSO
// streams each row to perm[] (contiguous, node-sorted; coalesced posted stores), and
// P3 re-reads perm[] SEQUENTIALLY -> second sweep leaves the random-gather regime
// (theory: per-CU outstanding-miss cap ~2.5 TB/s pins random 512B gathers; streaming
// full-line reads are not so capped). PERM=0: exact round-5 fallback (ws too small).
template<int PERM>
__global__ __launch_bounds__(128, 4) void mega_kernel(
    const float* __restrict__ msg, const int* __restrict__ eidx,
    const int* __restrict__ start, float* __restrict__ perm,
    const float* __restrict__ Wqk, const float* __restrict__ bqk,
    const float* __restrict__ wqb, const float* __restrict__ bqbp,
    const float* __restrict__ Wvo, const float* __restrict__ bvo,
    const float* __restrict__ bo,
    float* __restrict__ out, int N) {
    __shared__ float4 sums4[NPB * 32];   // 4KB: sums, later reused as normalized S
    __shared__ float4 qks4[NPB * 32];    // 4KB
    __shared__ int eidx_s[CAP];          // 1.15KB: block's edge ids
    __shared__ float sat[NPB];

    int t = threadIdx.x;
    int lane = t & 63, w = t >> 6;
    int h = lane >> 5;   // row parity within the stream
    int k = lane & 31;   // float4 feature chunk
    int base = blockIdx.x * NPB;
    const float4* msg4 = (const float4*)msg;
    float4* perm4w = (float4*)perm;
    const float4* perm4c = (const float4*)perm;

    int nendB = min(base + NPB, N);
    int s0B = start[base];
    int cntB = start[nendB] - s0B;
    int cc = min(cntB, CAP);
    for (int i = t; i < cc; i += 128) eidx_s[i] = eidx[s0B + i];

    int n0 = base + w * 4;
    int b0 = start[min(n0 + 0, N)] - s0B;
    int b1 = start[min(n0 + 1, N)] - s0B;
    int b2 = start[min(n0 + 2, N)] - s0B;
    int b3 = start[min(n0 + 3, N)] - s0B;
    int b4 = start[min(n0 + 4, N)] - s0B;

    __syncthreads();

    auto loadrow = [&](int r) -> float4 {   // P1: random gather via edge ids
        int rI = min(r, b4 - 1);
        int e = (rI < CAP) ? eidx_s[rI] : eidx[s0B + rI];
        return msg4[(size_t)e * 32 + k];
    };
    auto loadrowP = [&](int r) -> float4 {  // P3 (PERM): contiguous stream
        int rI = min(r, b4 - 1);
        if (PERM) return perm4c[(size_t)(s0B + rI) * 32 + k];
        else      return loadrow(rI);
    };

    // ---- P1: per-node sums, flat stream, 8 rows/iter, 2-stage pipeline (+perm store) ----
    float4 a0 = Z4, a1 = Z4, a2 = Z4, a3 = Z4;
    if (b0 < b4) {
        int j = b0;
        float4 F0 = loadrow(j + h), F1 = loadrow(j + h + 2),
               F2 = loadrow(j + h + 4), F3 = loadrow(j + h + 6);
        for (;;) {
            int jn = j + 8;
            bool more = jn < b4;
            float4 G0, G1, G2, G3;
            if (more) {
                G0 = loadrow(jn + h); G1 = loadrow(jn + h + 2);
                G2 = loadrow(jn + h + 4); G3 = loadrow(jn + h + 6);
            }
            P1STEP(0, F0); P1STEP(1, F1); P1STEP(2, F2); P1STEP(3, F3);
            if (!more) break;
            F0 = G0; F1 = G1; F2 = G2; F3 = G3;
            j = jn;
        }
    }
    MRG4(a0); MRG4(a1); MRG4(a2); MRG4(a3);
    if (lane < 32) {
        sums4[(w * 4 + 0) * 32 + k] = a0;
        sums4[(w * 4 + 1) * 32 + k] = a1;
        sums4[(w * 4 + 2) * 32 + k] = a2;
        sums4[(w * 4 + 3) * 32 + k] = a3;
    }
    __syncthreads();   // also drains perm stores (vmcnt 0 before barrier)

    // ---- P2: qk = sums @ Wqk + bqk  (slot 0..3 handles nodes slot, slot+4) ----
    {
        int c = t & 31, slot = t >> 5;
        const float4* B4 = (const float4*)Wqk;
        float4 acc0 = ((const float4*)bqk)[c];
        float4 acc1 = acc0;
        for (int i = 0; i < D; i += 4) {
            float4 aA = sums4[slot * 32 + (i >> 2)];
            float4 aB = sums4[(slot + 4) * 32 + (i >> 2)];
            float4 c0 = B4[(i + 0) * 32 + c];
            float4 c1 = B4[(i + 1) * 32 + c];
            float4 c2 = B4[(i + 2) * 32 + c];
            float4 c3 = B4[(i + 3) * 32 + c];
            FMA4(acc0, aA.x, c0); FMA4(acc0, aA.y, c1); FMA4(acc0, aA.z, c2); FMA4(acc0, aA.w, c3);
            FMA4(acc1, aB.x, c0); FMA4(acc1, aB.y, c1); FMA4(acc1, aB.z, c2); FMA4(acc1, aB.w, c3);
        }
        qks4[slot * 32 + c] = acc0;
        qks4[(slot + 4) * 32 + c] = acc1;
    }
    __syncthreads();

    // ---- P3: single-sweep defer-max online softmax (PERM: sequential reads) ----
    {
        float4 wv = ((const float4*)wqb)[k];
        float bqb = bqbp[0];
        float4 sv0 = sums4[(w * 4 + 0) * 32 + k];
        float4 sv1 = sums4[(w * 4 + 1) * 32 + k];
        float4 sv2 = sums4[(w * 4 + 2) * 32 + k];
        float4 sv3 = sums4[(w * 4 + 3) * 32 + k];
        float qb0 = hdot32(sv0, wv) + bqb;
        float qb1 = hdot32(sv1, wv) + bqb;
        float qb2 = hdot32(sv2, wv) + bqb;
        float qb3 = hdot32(sv3, wv) + bqb;
        float4 q0 = qks4[(w * 4 + 0) * 32 + k];
        float4 q1 = qks4[(w * 4 + 1) * 32 + k];
        float4 q2 = qks4[(w * 4 + 2) * 32 + k];
        float4 q3 = qks4[(w * 4 + 3) * 32 + k];

        float m0 = NEG_HUGE, m1 = NEG_HUGE, m2 = NEG_HUGE, m3 = NEG_HUGE;
        float sm0 = 0.f, sm1 = 0.f, sm2 = 0.f, sm3 = 0.f;
        float4 c0 = Z4, c1 = Z4, c2 = Z4, c3 = Z4;
        if (b0 < b4) {
            int j = b0;
            float4 F0 = loadrowP(j + h), F1 = loadrowP(j + h + 2),
                   F2 = loadrowP(j + h + 4), F3 = loadrowP(j + h + 6);
            for (;;) {
                int jn = j + 8;
                bool more = jn < b4;
                float4 G0, G1, G2, G3;
                if (more) {
                    G0 = loadrowP(jn + h); G1 = loadrowP(jn + h + 2);
                    G2 = loadrowP(jn + h + 4); G3 = loadrowP(jn + h + 6);
                }
                P3STEP(0, F0); P3STEP(1, F1); P3STEP(2, F2); P3STEP(3, F3);
                if (!more) break;
                F0 = G0; F1 = G1; F2 = G2; F3 = G3;
                j = jn;
            }
        }
        MERGE_HALVES(m0, sm0, c0);
        MERGE_HALVES(m1, sm1, c1);
        MERGE_HALVES(m2, sm2, c2);
        MERGE_HALVES(m3, sm3, c3);
        float inv0 = 1.f / (sm0 + 1e-8f);
        float inv1 = 1.f / (sm1 + 1e-8f);
        float inv2 = 1.f / (sm2 + 1e-8f);
        float inv3 = 1.f / (sm3 + 1e-8f);
        if (lane < 32) {
            sums4[(w * 4 + 0) * 32 + k] = make_float4(c0.x * inv0, c0.y * inv0, c0.z * inv0, c0.w * inv0);
            sums4[(w * 4 + 1) * 32 + k] = make_float4(c1.x * inv1, c1.y * inv1, c1.z * inv1, c1.w * inv1);
            sums4[(w * 4 + 2) * 32 + k] = make_float4(c2.x * inv2, c2.y * inv2, c2.z * inv2, c2.w * inv2);
            sums4[(w * 4 + 3) * 32 + k] = make_float4(c3.x * inv3, c3.y * inv3, c3.z * inv3, c3.w * inv3);
        }
        if (lane == 0) {
            sat[w * 4 + 0] = sm0 * inv0;
            sat[w * 4 + 1] = sm1 * inv1;
            sat[w * 4 + 2] = sm2 * inv2;
            sat[w * 4 + 3] = sm3 * inv3;
        }
    }
    __syncthreads();

    // ---- P4: out = S @ Wvo + sat*bvo + bo ----
    {
        int c = t & 31, slot = t >> 5;
        const float4* B4 = (const float4*)Wvo;
        float4 bo4 = ((const float4*)bo)[c];
        float4 bv4 = ((const float4*)bvo)[c];
        float sa0 = sat[slot], sa1 = sat[slot + 4];
        float4 acc0 = make_float4(bo4.x + sa0 * bv4.x, bo4.y + sa0 * bv4.y,
                                  bo4.z + sa0 * bv4.z, bo4.w + sa0 * bv4.w);
        float4 acc1 = make_float4(bo4.x + sa1 * bv4.x, bo4.y + sa1 * bv4.y,
                                  bo4.z + sa1 * bv4.z, bo4.w + sa1 * bv4.w);
        for (int i = 0; i < D; i += 4) {
            float4 aA = sums4[slot * 32 + (i >> 2)];
            float4 aB = sums4[(slot + 4) * 32 + (i >> 2)];
            float4 d0 = B4[(i + 0) * 32 + c];
            float4 d1 = B4[(i + 1) * 32 + c];
            float4 d2 = B4[(i + 2) * 32 + c];
            float4 d3 = B4[(i + 3) * 32 + c];
            FMA4(acc0, aA.x, d0); FMA4(acc0, aA.y, d1); FMA4(acc0, aA.z, d2); FMA4(acc0, aA.w, d3);
            FMA4(acc1, aB.x, d0); FMA4(acc1, aB.y, d1); FMA4(acc1, aB.z, d2); FMA4(acc1, aB.w, d3);
        }
        int nA = base + slot, nB = base + slot + 4;
        if (nA < N) ((float4*)(out + (size_t)nA * D))[c] = acc0;
        if (nB < N) ((float4*)(out + (size_t)nB * D))[c] = acc1;
    }
}

// ============================ launch ============================

extern "C" void kernel_launch(void* const* d_in, const int* in_sizes, int n_in,
                              void* d_out, int out_size, void* d_ws, size_t ws_size,
                              hipStream_t stream) {
    const float* msg = (const float*)d_in[0];
    const int* recv = (const int*)d_in[1];
    const float* Wk = (const float*)d_in[3];
    const float* bk = (const float*)d_in[4];
    const float* Wv = (const float*)d_in[5];
    const float* bv = (const float*)d_in[6];
    const float* Wq = (const float*)d_in[7];
    const float* bq = (const float*)d_in[8];
    const float* Wo = (const float*)d_in[9];
    const float* bo = (const float*)d_in[10];
    float* out = (float*)d_out;

    int E = in_sizes[0] / D;
    int N = out_size / D;

    char* wsb = (char*)d_ws;
    size_t o = 0;
    auto alloc = [&](size_t elems) {
        void* p = wsb + o;
        o += (elems * 4 + 63) & ~(size_t)63;   // 64B-align each buffer
        return p;
    };

    int* cnt    = (int*)alloc(2 * (size_t)N);  // cnt + cursor in ONE block (contiguous zeroing)
    int* cursor = cnt + N;
    int* start  = (int*)alloc(N + 1);
    int* eidx   = (int*)alloc(E);
    float* Wqk  = (float*)alloc(D * D);
    float* bqk  = (float*)alloc(D);
    float* wqb  = (float*)alloc(D);
    float* bqb  = (float*)alloc(1);
    float* Wvo  = (float*)alloc(D * D);
    float* bvo  = (float*)alloc(D);
    // perm: node-sorted copy of messages (E x D floats). Guarded by ws_size.
    float* perm = (float*)(wsb + o);
    bool use_perm = (o + (size_t)E * D * 4) <= ws_size;

    int zcount = 2 * N;
    int zblocks = (zcount + 255) / 256;
    prep_kernel<<<65 + zblocks, 256, 0, stream>>>(Wq, Wk, bq, bk, Wv, Wo, bv,
                                                  Wqk, bqk, wqb, bqb, Wvo, bvo,
                                                  cnt, zcount);
    int E4 = (E + 3) / 4;
    int nbE4 = (E4 + 255) / 256;
    hist_kernel<<<nbE4, 256, 0, stream>>>(recv, cnt, E);
    scan_kernel<<<1, 1024, 0, stream>>>(cnt, start, N);
    int nbE = (E + 255) / 256;
    fill_kernel<<<nbE, 256, 0, stream>>>(recv, start, cursor, eidx, E);
    int nblk = (N + NPB - 1) / NPB;
    if (use_perm) {
        mega_kernel<1><<<nblk, 128, 0, stream>>>(msg, eidx, start, perm, Wqk, bqk, wqb, bqb,
                                                 Wvo, bvo, bo, out, N);
    } else {
        mega_kernel<0><<<nblk, 128, 0, stream>>>(msg, eidx, start, nullptr, Wqk, bqk, wqb, bqb,
                                                 Wvo, bvo, bo, out, N);
    }
}

// Round 9
// 680.732 us; speedup vs baseline: 1.0467x; 1.0467x over previous
//
#include <hip/hip_runtime.h>

#define D 128
#define RSQRT_D 0.088388347648318440550f  // 1/sqrt(128)
#define NEG_HUGE -3.4e38f
#define NPB 8     // nodes per block (2 waves x 4 nodes)
#define CAP 288   // LDS-cached edge indices per block (mean demand 128, +14 sigma)
#define DTHR 20.0f  // defer-max rescale threshold

#define FMA4(acc, s, b) { acc.x += (s)*(b).x; acc.y += (s)*(b).y; acc.z += (s)*(b).z; acc.w += (s)*(b).w; }
#define ADD4(acc, b) { acc.x += (b).x; acc.y += (b).y; acc.z += (b).z; acc.w += (b).w; }
#define MRG4(a) { a.x += __shfl_xor(a.x,32); a.y += __shfl_xor(a.y,32); a.z += __shfl_xor(a.z,32); a.w += __shfl_xor(a.w,32); }
#define SCL4(a, f) { a.x *= (f); a.y *= (f); a.z *= (f); a.w *= (f); }
#define Z4 make_float4(0.f,0.f,0.f,0.f)

// merge softmax state (m,s,c) across the two half-waves
#define MERGE_HALVES(mi, si, ci) { \
    float mo_ = __shfl_xor(mi, 32); \
    float so_ = __shfl_xor(si, 32); \
    float4 co_; co_.x = __shfl_xor(ci.x, 32); co_.y = __shfl_xor(ci.y, 32); \
    co_.z = __shfl_xor(ci.z, 32); co_.w = __shfl_xor(ci.w, 32); \
    float mt_ = fmaxf(mi, mo_); \
    float e0_ = __expf(mi - mt_), e1_ = __expf(mo_ - mt_); \
    si = si * e0_ + so_ * e1_; \
    ci.x = ci.x * e0_ + co_.x * e1_; ci.y = ci.y * e0_ + co_.y * e1_; \
    ci.z = ci.z * e0_ + co_.z * e1_; ci.w = ci.w * e0_ + co_.w * e1_; \
}

// ---------------- prep: weight folds + zero cnt/cursor ----------------
__global__ __launch_bounds__(256) void prep_kernel(
    const float* __restrict__ Wq, const float* __restrict__ Wk,
    const float* __restrict__ bq, const float* __restrict__ bk,
    const float* __restrict__ Wv, const float* __restrict__ Wo,
    const float* __restrict__ bv,
    float* __restrict__ Wqk, float* __restrict__ bqk,
    float* __restrict__ wqb, float* __restrict__ bqb,
    float* __restrict__ Wvo, float* __restrict__ bvo,
    int* __restrict__ zbase, int zcount) {
    int bid = blockIdx.x, t = threadIdx.x;
    if (bid < 64) {
        int i = bid * 2 + (t >> 7), j = t & 127;
        float a1 = 0.f, a2 = 0.f;
        for (int u = 0; u < D; ++u) {
            a1 += Wq[i * D + u] * Wk[j * D + u];   // (Wq @ Wk^T)[i][j]
            a2 += Wv[i * D + u] * Wo[u * D + j];   // (Wv @ Wo)[i][j]
        }
        Wqk[i * D + j] = a1;
        Wvo[i * D + j] = a2;
    } else if (bid == 64) {
        if (t < D) {
            int j = t;
            float a1 = 0.f, a2 = 0.f, a3 = 0.f;
            for (int u = 0; u < D; ++u) {
                a1 += bq[u] * Wk[j * D + u];       // bq @ Wk^T
                a2 += Wq[j * D + u] * bk[u];       // Wq @ bk
                a3 += bv[u] * Wo[u * D + j];       // bv @ Wo
            }
            bqk[j] = a1; wqb[j] = a2; bvo[j] = a3;
            if (j == 0) {
                float b = 0.f;
                for (int u = 0; u < D; ++u) b += bq[u] * bk[u];
                *bqb = b;
            }
        }
    } else {
        int idx = (bid - 65) * 256 + t;
        if (idx < zcount) zbase[idx] = 0;
    }
}

// ---------------- CSR: histogram (int4 recv loads; counts are order-invariant) ----------------
__global__ void hist_kernel(const int* __restrict__ recv, int* __restrict__ cnt, int E) {
    int i = blockIdx.x * blockDim.x + threadIdx.x;
    int base = i << 2;
    if (base + 3 < E) {
        int4 r = *(const int4*)(recv + base);
        atomicAdd(&cnt[r.x], 1);
        atomicAdd(&cnt[r.y], 1);
        atomicAdd(&cnt[r.z], 1);
        atomicAdd(&cnt[r.w], 1);
    } else {
        for (int u = base; u < E; ++u) atomicAdd(&cnt[recv[u]], 1);
    }
}

// ---------------- CSR: single-block exclusive scan (int4-wide, prefetched) ----------------
__global__ __launch_bounds__(1024) void scan_kernel(const int* __restrict__ cnt,
                                                    int* __restrict__ start, int N) {
    __shared__ int wsum[16];
    __shared__ int chunk_total;
    int t = threadIdx.x;
    int w = t >> 6, lane = t & 63;
    int running = 0;
    const int4* cnt4 = (const int4*)cnt;
    int nIter = (N + 4095) >> 12;   // 4096 elems per iteration
    int4 v = make_int4(0, 0, 0, 0);
    {
        int i = t << 2;
        if (i < N) v = cnt4[i >> 2];   // N % 4 == 0
    }
    for (int it = 0; it < nIter; ++it) {
        int4 vn = make_int4(0, 0, 0, 0);
        {
            int i = ((it + 1) << 12) + (t << 2);
            if (it + 1 < nIter && i < N) vn = cnt4[i >> 2];
        }
        int s0 = v.x, s1 = s0 + v.y, s2 = s1 + v.z, s3 = s2 + v.w;  // thread-local inclusive
        int x = s3;
#pragma unroll
        for (int off = 1; off < 64; off <<= 1) {
            int y = __shfl_up(x, off);
            if (lane >= off) x += y;
        }
        if (lane == 63) wsum[w] = x;
        __syncthreads();
        if (w == 0 && lane < 16) {
            int s = wsum[lane];
#pragma unroll
            for (int off = 1; off < 16; off <<= 1) {
                int y = __shfl_up(s, off);
                if (lane >= off) s += y;
            }
            wsum[lane] = s;  // inclusive
            if (lane == 15) chunk_total = s;
        }
        __syncthreads();
        int waveoff = (w == 0) ? 0 : wsum[w - 1];
        int tb = running + waveoff + (x - s3);  // exclusive base for this thread's 4
        int i = (it << 12) + (t << 2);
        if (i < N) ((int4*)start)[i >> 2] = make_int4(tb, tb + s0, tb + s1, tb + s2);
        running += chunk_total;
        __syncthreads();
        v = vn;
    }
    if (t == 0) start[N] = running;
}

// ---------------- CSR: fill edge index lists (kept 1-thread/edge: preserves edge order) ----------------
__global__ void fill_kernel(const int* __restrict__ recv, const int* __restrict__ start,
                            int* __restrict__ cursor, int* __restrict__ eidx, int E) {
    int e = blockIdx.x * blockDim.x + threadIdx.x;
    if (e >= E) return;
    int r = recv[e];
    int p = atomicAdd(&cursor[r], 1);
    eidx[start[r] + p] = e;
}

// cross-half-wave dot: 32-lane reduce of per-lane float4 partial
__device__ __forceinline__ float hdot32(float4 f, float4 q) {
    float p = f.x * q.x + f.y * q.y + f.z * q.z + f.w * q.w;
    p += __shfl_xor(p, 1); p += __shfl_xor(p, 2); p += __shfl_xor(p, 4);
    p += __shfl_xor(p, 8); p += __shfl_xor(p, 16);
    return p;
}

// P1 per-row step (row r = j + h + 2u; accumulate into the owning node's partial)
#define P1STEP(u, Fx) { \
    int r = j + h + 2 * (u); \
    float4 g_ = Fx; \
    float mk_ = (r < b4) ? 1.f : 0.f; \
    g_.x *= mk_; g_.y *= mk_; g_.z *= mk_; g_.w *= mk_; \
    if (r < b1)      { ADD4(a0, g_); } \
    else if (r < b2) { ADD4(a1, g_); } \
    else if (r < b3) { ADD4(a2, g_); } \
    else             { ADD4(a3, g_); } \
}

// P3 per-row step: score -> defer-max -> weighted accumulate
#define P3STEP(u, Fx) { \
    int r = j + h + 2 * (u); \
    bool valid_ = r < b4; \
    float4 f_ = Fx; \
    float4 qv_ = (r < b1) ? q0 : (r < b2) ? q1 : (r < b3) ? q2 : q3; \
    float qbv_ = (r < b1) ? qb0 : (r < b2) ? qb1 : (r < b3) ? qb2 : qb3; \
    float sc_ = (hdot32(f_, qv_) + qbv_) * RSQRT_D; \
    float msel_ = (r < b1) ? m0 : (r < b2) ? m1 : (r < b3) ? m2 : m3; \
    if (valid_ && sc_ > msel_ + DTHR) { \
        float fac_ = __expf(msel_ - sc_); \
        if (r < b1)      { sm0 *= fac_; SCL4(c0, fac_); m0 = sc_; } \
        else if (r < b2) { sm1 *= fac_; SCL4(c1, fac_); m1 = sc_; } \
        else if (r < b3) { sm2 *= fac_; SCL4(c2, fac_); m2 = sc_; } \
        else             { sm3 *= fac_; SCL4(c3, fac_); m3 = sc_; } \
        msel_ = sc_; \
    } \
    float wgt_ = valid_ ? __expf(sc_ - msel_) : 0.f; \
    if (r < b1)      { sm0 += wgt_; FMA4(c0, wgt_, f_); } \
    else if (r < b2) { sm1 += wgt_; FMA4(c1, wgt_, f_); } \
    else if (r < b3) { sm2 += wgt_; FMA4(c2, wgt_, f_); } \
    else             { sm3 += wgt_; FMA4(c3, wgt_, f_); } \
}

// process one FIFO group of 8 rows starting at relative offset jo
#define P1G(jo, Ra, Rb, Rc, Rd) { int j = b0 + (jo); P1STEP(0, Ra); P1STEP(1, Rb); P1STEP(2, Rc); P1STEP(3, Rd); }
#define P3G(jo, Ra, Rb, Rc, Rd) { int j = b0 + (jo); P3STEP(0, Ra); P3STEP(1, Rb); P3STEP(2, Rc); P3STEP(3, Rd); }

// ---------------- mega: register-FIFO rows -> sums -> qk -> defer-max softmax -> out ----------------
// Round-5 geometry (128 thr, 2 waves x 4 nodes). NEW: the first 48 rows of each wave's
// edge range are loaded ONCE in P1 into 24 named float4 registers (half-wave interleaved)
// and kept live through P2 so P3 consumes them with ZERO memory requests (~75% of edges;
// mean range 64, sigma 8). Only the tail (rows >= 48) re-gathers in P3 (L3-hot).
// Rationale: delivery for L1-missing gathers is capped (~1.3 TB/s HBM-missing; rounds
// 1/4/6/7 showed occupancy/MLP don't move it) -> the lever is REQUEST ELIMINATION with
// no added traffic (round 8's perm attempt paid 327MB of writes for the same idea).
// __launch_bounds__(128,3): VGPR cap 170 for the ~150-reg working set, no spill.
__global__ __launch_bounds__(128, 3) void mega_kernel(
    const float* __restrict__ msg, const int* __restrict__ eidx,
    const int* __restrict__ start,
    const float* __restrict__ Wqk, const float* __restrict__ bqk,
    const float* __restrict__ wqb, const float* __restrict__ bqbp,
    const float* __restrict__ Wvo, const float* __restrict__ bvo,
    const float* __restrict__ bo,
    float* __restrict__ out, int N) {
    __shared__ float4 sums4[NPB * 32];   // 4KB: sums, later reused as normalized S
    __shared__ float4 qks4[NPB * 32];    // 4KB
    __shared__ int eidx_s[CAP];          // 1.15KB: block's edge ids
    __shared__ float sat[NPB];

    int t = threadIdx.x;
    int lane = t & 63, w = t >> 6;
    int h = lane >> 5;   // row parity within the stream
    int k = lane & 31;   // float4 feature chunk
    int base = blockIdx.x * NPB;
    const float4* msg4 = (const float4*)msg;

    int nendB = min(base + NPB, N);
    int s0B = start[base];
    int cntB = start[nendB] - s0B;
    int cc = min(cntB, CAP);
    for (int i = t; i < cc; i += 128) eidx_s[i] = eidx[s0B + i];

    int n0 = base + w * 4;
    int b0 = start[min(n0 + 0, N)] - s0B;
    int b1 = start[min(n0 + 1, N)] - s0B;
    int b2 = start[min(n0 + 2, N)] - s0B;
    int b3 = start[min(n0 + 3, N)] - s0B;
    int b4 = start[min(n0 + 4, N)] - s0B;

    __syncthreads();

    auto loadrow = [&](int r) -> float4 {
        int rI = min(r, b4 - 1);
        int e = (rI < CAP) ? eidx_s[rI] : eidx[s0B + rI];   // fallback: oversized block
        return msg4[(size_t)e * 32 + k];
    };

    // FIFO: rows b0+0..b0+47 of this wave's range, half-wave interleaved
    // (reg Rgu holds row b0 + 8g + 2u + h for lanes of half h).
    float4 R00 = Z4, R01 = Z4, R02 = Z4, R03 = Z4,
           R10 = Z4, R11 = Z4, R12 = Z4, R13 = Z4,
           R20 = Z4, R21 = Z4, R22 = Z4, R23 = Z4,
           R30 = Z4, R31 = Z4, R32 = Z4, R33 = Z4,
           R40 = Z4, R41 = Z4, R42 = Z4, R43 = Z4,
           R50 = Z4, R51 = Z4, R52 = Z4, R53 = Z4;

    // ---- P1: load FIFO (24 independent 1KB wave-loads in flight), accumulate sums ----
    float4 a0 = Z4, a1 = Z4, a2 = Z4, a3 = Z4;
    if (b0 < b4) {
        R00 = loadrow(b0 + h +  0); R01 = loadrow(b0 + h +  2); R02 = loadrow(b0 + h +  4); R03 = loadrow(b0 + h +  6);
        R10 = loadrow(b0 + h +  8); R11 = loadrow(b0 + h + 10); R12 = loadrow(b0 + h + 12); R13 = loadrow(b0 + h + 14);
        R20 = loadrow(b0 + h + 16); R21 = loadrow(b0 + h + 18); R22 = loadrow(b0 + h + 20); R23 = loadrow(b0 + h + 22);
        R30 = loadrow(b0 + h + 24); R31 = loadrow(b0 + h + 26); R32 = loadrow(b0 + h + 28); R33 = loadrow(b0 + h + 30);
        R40 = loadrow(b0 + h + 32); R41 = loadrow(b0 + h + 34); R42 = loadrow(b0 + h + 36); R43 = loadrow(b0 + h + 38);
        R50 = loadrow(b0 + h + 40); R51 = loadrow(b0 + h + 42); R52 = loadrow(b0 + h + 44); R53 = loadrow(b0 + h + 46);
        P1G( 0, R00, R01, R02, R03);
        P1G( 8, R10, R11, R12, R13);
        P1G(16, R20, R21, R22, R23);
        P1G(24, R30, R31, R32, R33);
        P1G(32, R40, R41, R42, R43);
        P1G(40, R50, R51, R52, R53);
        // tail: rows >= 48, 4 rows/iter 2-stage pipeline (lean on registers)
        int j = b0 + 48;
        if (j < b4) {
            float4 F0 = loadrow(j + h), F1 = loadrow(j + h + 2);
            for (;;) {
                int jn = j + 4;
                bool more = jn < b4;
                float4 G0, G1;
                if (more) { G0 = loadrow(jn + h); G1 = loadrow(jn + h + 2); }
                P1STEP(0, F0); P1STEP(1, F1);
                if (!more) break;
                F0 = G0; F1 = G1; j = jn;
            }
        }
    }
    MRG4(a0); MRG4(a1); MRG4(a2); MRG4(a3);
    if (lane < 32) {
        sums4[(w * 4 + 0) * 32 + k] = a0;
        sums4[(w * 4 + 1) * 32 + k] = a1;
        sums4[(w * 4 + 2) * 32 + k] = a2;
        sums4[(w * 4 + 3) * 32 + k] = a3;
    }
    __syncthreads();

    // ---- P2: qk = sums @ Wqk + bqk  (slot 0..3 handles nodes slot, slot+4) ----
    {
        int c = t & 31, slot = t >> 5;
        const float4* B4 = (const float4*)Wqk;
        float4 acc0 = ((const float4*)bqk)[c];
        float4 acc1 = acc0;
        for (int i = 0; i < D; i += 4) {
            float4 aA = sums4[slot * 32 + (i >> 2)];
            float4 aB = sums4[(slot + 4) * 32 + (i >> 2)];
            float4 w0 = B4[(i + 0) * 32 + c];
            float4 w1 = B4[(i + 1) * 32 + c];
            float4 w2 = B4[(i + 2) * 32 + c];
            float4 w3 = B4[(i + 3) * 32 + c];
            FMA4(acc0, aA.x, w0); FMA4(acc0, aA.y, w1); FMA4(acc0, aA.z, w2); FMA4(acc0, aA.w, w3);
            FMA4(acc1, aB.x, w0); FMA4(acc1, aB.y, w1); FMA4(acc1, aB.z, w2); FMA4(acc1, aB.w, w3);
        }
        qks4[slot * 32 + c] = acc0;
        qks4[(slot + 4) * 32 + c] = acc1;
    }
    __syncthreads();

    // ---- P3: single-sweep defer-max softmax; FIFO rows need NO memory access ----
    {
        float4 wv = ((const float4*)wqb)[k];
        float bqb = bqbp[0];
        float4 sv0 = sums4[(w * 4 + 0) * 32 + k];
        float4 sv1 = sums4[(w * 4 + 1) * 32 + k];
        float4 sv2 = sums4[(w * 4 + 2) * 32 + k];
        float4 sv3 = sums4[(w * 4 + 3) * 32 + k];
        float qb0 = hdot32(sv0, wv) + bqb;
        float qb1 = hdot32(sv1, wv) + bqb;
        float qb2 = hdot32(sv2, wv) + bqb;
        float qb3 = hdot32(sv3, wv) + bqb;
        float4 q0 = qks4[(w * 4 + 0) * 32 + k];
        float4 q1 = qks4[(w * 4 + 1) * 32 + k];
        float4 q2 = qks4[(w * 4 + 2) * 32 + k];
        float4 q3 = qks4[(w * 4 + 3) * 32 + k];

        float m0 = NEG_HUGE, m1 = NEG_HUGE, m2 = NEG_HUGE, m3 = NEG_HUGE;
        float sm0 = 0.f, sm1 = 0.f, sm2 = 0.f, sm3 = 0.f;
        float4 c0 = Z4, c1 = Z4, c2 = Z4, c3 = Z4;
        if (b0 < b4) {
            P3G( 0, R00, R01, R02, R03);
            P3G( 8, R10, R11, R12, R13);
            P3G(16, R20, R21, R22, R23);
            P3G(24, R30, R31, R32, R33);
            P3G(32, R40, R41, R42, R43);
            P3G(40, R50, R51, R52, R53);
            // tail: rows >= 48, re-gather (mostly L3-hot from P1)
            int j = b0 + 48;
            if (j < b4) {
                float4 F0 = loadrow(j + h), F1 = loadrow(j + h + 2);
                for (;;) {
                    int jn = j + 4;
                    bool more = jn < b4;
                    float4 G0, G1;
                    if (more) { G0 = loadrow(jn + h); G1 = loadrow(jn + h + 2); }
                    P3STEP(0, F0); P3STEP(1, F1);
                    if (!more) break;
                    F0 = G0; F1 = G1; j = jn;
                }
            }
        }
        MERGE_HALVES(m0, sm0, c0);
        MERGE_HALVES(m1, sm1, c1);
        MERGE_HALVES(m2, sm2, c2);
        MERGE_HALVES(m3, sm3, c3);
        float inv0 = 1.f / (sm0 + 1e-8f);
        float inv1 = 1.f / (sm1 + 1e-8f);
        float inv2 = 1.f / (sm2 + 1e-8f);
        float inv3 = 1.f / (sm3 + 1e-8f);
        if (lane < 32) {
            sums4[(w * 4 + 0) * 32 + k] = make_float4(c0.x * inv0, c0.y * inv0, c0.z * inv0, c0.w * inv0);
            sums4[(w * 4 + 1) * 32 + k] = make_float4(c1.x * inv1, c1.y * inv1, c1.z * inv1, c1.w * inv1);
            sums4[(w * 4 + 2) * 32 + k] = make_float4(c2.x * inv2, c2.y * inv2, c2.z * inv2, c2.w * inv2);
            sums4[(w * 4 + 3) * 32 + k] = make_float4(c3.x * inv3, c3.y * inv3, c3.z * inv3, c3.w * inv3);
        }
        if (lane == 0) {
            sat[w * 4 + 0] = sm0 * inv0;
            sat[w * 4 + 1] = sm1 * inv1;
            sat[w * 4 + 2] = sm2 * inv2;
            sat[w * 4 + 3] = sm3 * inv3;
        }
    }
    __syncthreads();

    // ---- P4: out = S @ Wvo + sat*bvo + bo ----
    {
        int c = t & 31, slot = t >> 5;
        const float4* B4 = (const float4*)Wvo;
        float4 bo4 = ((const float4*)bo)[c];
        float4 bv4 = ((const float4*)bvo)[c];
        float sa0 = sat[slot], sa1 = sat[slot + 4];
        float4 acc0 = make_float4(bo4.x + sa0 * bv4.x, bo4.y + sa0 * bv4.y,
                                  bo4.z + sa0 * bv4.z, bo4.w + sa0 * bv4.w);
        float4 acc1 = make_float4(bo4.x + sa1 * bv4.x, bo4.y + sa1 * bv4.y,
                                  bo4.z + sa1 * bv4.z, bo4.w + sa1 * bv4.w);
        for (int i = 0; i < D; i += 4) {
            float4 aA = sums4[slot * 32 + (i >> 2)];
            float4 aB = sums4[(slot + 4) * 32 + (i >> 2)];
            float4 d0 = B4[(i + 0) * 32 + c];
            float4 d1 = B4[(i + 1) * 32 + c];
            float4 d2 = B4[(i + 2) * 32 + c];
            float4 d3 = B4[(i + 3) * 32 + c];
            FMA4(acc0, aA.x, d0); FMA4(acc0, aA.y, d1); FMA4(acc0, aA.z, d2); FMA4(acc0, aA.w, d3);
            FMA4(acc1, aB.x, d0); FMA4(acc1, aB.y, d1); FMA4(acc1, aB.z, d2); FMA4(acc1, aB.w, d3);
        }
        int nA = base + slot, nB = base + slot + 4;
        if (nA < N) ((float4*)(out + (size_t)nA * D))[c] = acc0;
        if (nB < N) ((float4*)(out + (size_t)nB * D))[c] = acc1;
    }
}

// ============================ launch ============================

extern "C" void kernel_launch(void* const* d_in, const int* in_sizes, int n_in,
                              void* d_out, int out_size, void* d_ws, size_t ws_size,
                              hipStream_t stream) {
    const float* msg = (const float*)d_in[0];
    const int* recv = (const int*)d_in[1];
    const float* Wk = (const float*)d_in[3];
    const float* bk = (const float*)d_in[4];
    const float* Wv = (const float*)d_in[5];
    const float* bv = (const float*)d_in[6];
    const float* Wq = (const float*)d_in[7];
    const float* bq = (const float*)d_in[8];
    const float* Wo = (const float*)d_in[9];
    const float* bo = (const float*)d_in[10];
    float* out = (float*)d_out;

    int E = in_sizes[0] / D;
    int N = out_size / D;

    char* wsb = (char*)d_ws;
    size_t o = 0;
    auto alloc = [&](size_t elems) {
        void* p = wsb + o;
        o += (elems * 4 + 63) & ~(size_t)63;   // 64B-align each buffer
        return p;
    };

    int* cnt    = (int*)alloc(2 * (size_t)N);  // cnt + cursor in ONE block (contiguous zeroing)
    int* cursor = cnt + N;
    int* start  = (int*)alloc(N + 1);
    int* eidx   = (int*)alloc(E);
    float* Wqk  = (float*)alloc(D * D);
    float* bqk  = (float*)alloc(D);
    float* wqb  = (float*)alloc(D);
    float* bqb  = (float*)alloc(1);
    float* Wvo  = (float*)alloc(D * D);
    float* bvo  = (float*)alloc(D);

    int zcount = 2 * N;
    int zblocks = (zcount + 255) / 256;
    prep_kernel<<<65 + zblocks, 256, 0, stream>>>(Wq, Wk, bq, bk, Wv, Wo, bv,
                                                  Wqk, bqk, wqb, bqb, Wvo, bvo,
                                                  cnt, zcount);
    int E4 = (E + 3) / 4;
    int nbE4 = (E4 + 255) / 256;
    hist_kernel<<<nbE4, 256, 0, stream>>>(recv, cnt, E);
    scan_kernel<<<1, 1024, 0, stream>>>(cnt, start, N);
    int nbE = (E + 255) / 256;
    fill_kernel<<<nbE, 256, 0, stream>>>(recv, start, cursor, eidx, E);
    mega_kernel<<<(N + NPB - 1) / NPB, 128, 0, stream>>>(msg, eidx, start, Wqk, bqk, wqb, bqb,
                                                         Wvo, bvo, bo, out, N);
}